// Round 4
// baseline (449.430 us; speedup 1.0000x reference)
//
#include <hip/hip_runtime.h>
#include <hip/hip_bf16.h>
#include <stdint.h>

// LightNet attention fwd. B=2, T=2048, HID=1024, H=8, DK=DV=128, LR=128.
//
// Reduction: z=logcumsumexp(k) => exp(g_t)=E_{t-1}/E_t, khat=e_t/E_t with
// e_t=exp(k_t), E_t=cumsum(e). The scan telescopes to
//   o_t[v] = scale * sum_k (q_t[k]/E_t[k]) * sum_{s<=t} e_s[k] v_s[v]
// Chunked Tc=128: pass1 per-chunk Esum/U=e^T V; pass2 exclusive chunk prefix;
// pass3 intra(causal qn@e^T @ V) + inter(qn@Cprev).
//
// Contract (established by rounds 1-3): inputs fp32 (reads as bf16 NaN'd),
// OUTPUT fp32 (bf16 out gave finite full-scale error == fp32 reader hitting
// bf16 pairs). Inputs canonicalized to bf16 in ws; final GEMM emits fp32.

typedef short short8 __attribute__((ext_vector_type(8)));
typedef float f32x4 __attribute__((ext_vector_type(4)));

#define T_SEQ 2048
#define HIDN  1024
#define SCALE 0.08838834764831845f   // 128^-0.5

// ---------------- bf16 bit helpers ----------------
__device__ __forceinline__ float blo(unsigned int u){
  union{unsigned int i; float f;} v; v.i = u << 16; return v.f;
}
__device__ __forceinline__ float bhi(unsigned int u){
  union{unsigned int i; float f;} v; v.i = u & 0xffff0000u; return v.f;
}
__device__ __forceinline__ float bu2f(unsigned short u){
  union{unsigned int i; float f;} v; v.i = ((unsigned int)u) << 16; return v.f;
}
__device__ __forceinline__ unsigned short f2bu(float f){
  union{float f; unsigned int i;} v; v.f = f;
  unsigned int x = v.i;
  x += 0x7fffu + ((x >> 16) & 1u);     // RNE
  return (unsigned short)(x >> 16);
}
__device__ __forceinline__ void up8(const unsigned short* p, float* f){
  uint4 v = *(const uint4*)p;
  f[0]=blo(v.x); f[1]=bhi(v.x); f[2]=blo(v.y); f[3]=bhi(v.y);
  f[4]=blo(v.z); f[5]=bhi(v.z); f[6]=blo(v.w); f[7]=bhi(v.w);
}

// ---------------- dtype detect + canonicalize ----------------
// fp32 data read as fp32 is sane; bf16 data read as fp32 is ALSO mostly sane
// (≈ the high element), but fp32-as-bf16 NaN'd rounds 1/2, so inputs are
// established fp32. Detector kept as cheap insurance.
__global__ void detect_dtype(const float* __restrict__ X, int* __restrict__ flag){
  __shared__ int cnt;
  if (threadIdx.x == 0) cnt = 0;
  __syncthreads();
  float x = X[threadIdx.x];
  int sane = (fabsf(x) < 1e6f && (x == 0.f || fabsf(x) > 1e-20f)) ? 1 : 0;
  atomicAdd(&cnt, sane);
  __syncthreads();
  if (threadIdx.x == 0) *flag = (cnt >= 192) ? 1 : 0;   // 1 => inputs fp32
}

__global__ void convert_input(const void* __restrict__ src,
                              unsigned short* __restrict__ dst, int n,
                              const int* __restrict__ flag){
  int i = blockIdx.x * blockDim.x + threadIdx.x;
  int stride = gridDim.x * blockDim.x;
  if (*flag){
    const float* s = (const float*)src;
    for (; i < n; i += stride) dst[i] = f2bu(s[i]);
  } else {
    const unsigned short* s = (const unsigned short*)src;
    for (; i < n; i += stride) dst[i] = s[i];
  }
}

// ---------------- MFMA GEMM core: C(128x128) = A @ B^T, bf16, fp32 acc ----
// A [M][K] bf16 bits, B [N][K] bf16 bits, lda=ldb=K. 256 threads.
__device__ __forceinline__ void gemm_core(
    const unsigned short* __restrict__ A, const unsigned short* __restrict__ B,
    int K, int row0, int col0,
    unsigned short* sA, unsigned short* sB, f32x4 acc[4][4], int tid)
{
  const int lane = tid & 63;
  const int wm = (tid >> 6) & 1, wn = tid >> 7;
  for (int k0 = 0; k0 < K; k0 += 32){
    uint4 ra[2], rb[2];
#pragma unroll
    for (int r = 0; r < 2; ++r){
      int idx  = r*256 + tid;              // 512 chunks of 16B per tile
      int mrow = idx >> 2, kc = (idx & 3) * 8;
      ra[r] = *(const uint4*)(A + (size_t)(row0 + mrow)*K + k0 + kc);
      rb[r] = *(const uint4*)(B + (size_t)(col0 + mrow)*K + k0 + kc);
    }
    __syncthreads();                       // previous iter's LDS reads done
#pragma unroll
    for (int r = 0; r < 2; ++r){
      int idx = r*256 + tid;
      *(uint4*)(sA + idx*8) = ra[r];
      *(uint4*)(sB + idx*8) = rb[r];
    }
    __syncthreads();                       // LDS writes visible
    short8 av[4], bv[4];
#pragma unroll
    for (int i=0;i<4;i++)
      av[i] = *(const short8*)(sA + (size_t)(wm*64 + i*16 + (lane&15))*32 + (lane>>4)*8);
#pragma unroll
    for (int j=0;j<4;j++)
      bv[j] = *(const short8*)(sB + (size_t)(wn*64 + j*16 + (lane&15))*32 + (lane>>4)*8);
#pragma unroll
    for (int i=0;i<4;i++)
#pragma unroll
      for (int j=0;j<4;j++)
        acc[i][j] = __builtin_amdgcn_mfma_f32_16x16x32_bf16(av[i], bv[j], acc[i][j], 0, 0, 0);
  }
}

// act: 0 none, 1 silu/swish. Writes fp32 (Cf) or bf16 (Cb).
__device__ __forceinline__ void epilogue_store(
    f32x4 acc[4][4], int row0, int col0, int tid, int ldc, int act,
    float* __restrict__ Cf, unsigned short* __restrict__ Cb)
{
  const int lane = tid & 63;
  const int wm = (tid >> 6) & 1, wn = tid >> 7;
#pragma unroll
  for (int i=0;i<4;i++){
    int rbase = row0 + wm*64 + i*16 + ((lane>>4)<<2);
#pragma unroll
    for (int j=0;j<4;j++){
      int col = col0 + wn*64 + j*16 + (lane&15);
#pragma unroll
      for (int r=0;r<4;r++){
        float v = acc[i][j][r];
        if (act) v = v / (1.f + __expf(-v));
        if (Cf) Cf[(size_t)(rbase + r)*ldc + col] = v;
        else    Cb[(size_t)(rbase + r)*ldc + col] = f2bu(v);
      }
    }
  }
}

// Fused QKV+G1 projection. grid (32, 25): y<8 ->Q(silu), <16 ->K, <24 ->V,
// ==24 ->G1 (ldc=128).
__global__ __launch_bounds__(256, 2) void proj_kernel(
    const unsigned short* __restrict__ X,
    const unsigned short* __restrict__ Wq, const unsigned short* __restrict__ Wk,
    const unsigned short* __restrict__ Wv, const unsigned short* __restrict__ Wg1,
    unsigned short* __restrict__ Qb, unsigned short* __restrict__ Kb,
    unsigned short* __restrict__ Vb, unsigned short* __restrict__ G1b)
{
  __shared__ unsigned short sA[128*32], sB[128*32];
  int tid = threadIdx.x;
  int which = blockIdx.y >> 3;
  const unsigned short* Bp = (which==0)?Wq:(which==1)?Wk:(which==2)?Wv:Wg1;
  int row0 = blockIdx.x * 128;
  int col0 = (which==3) ? 0 : (blockIdx.y & 7) * 128;
  f32x4 acc[4][4] = {};
  gemm_core(X, Bp, HIDN, row0, col0, sA, sB, acc, tid);
  if      (which==0) epilogue_store(acc,row0,col0,tid,HIDN,1,nullptr,Qb);
  else if (which==1) epilogue_store(acc,row0,col0,tid,HIDN,0,nullptr,Kb);
  else if (which==2) epilogue_store(acc,row0,col0,tid,HIDN,0,nullptr,Vb);
  else               epilogue_store(acc,row0,col0,tid,128 ,0,nullptr,G1b);
}

// Generic A@B^T: gate (K=128, act=1 -> swish(gate), bf16) and final output
// GEMM (fp32 out).
__global__ __launch_bounds__(256, 2) void gemm_bt(
    const unsigned short* __restrict__ A, const unsigned short* __restrict__ B,
    int K, int ldc, int act, float* __restrict__ Cf,
    unsigned short* __restrict__ Cb)
{
  __shared__ unsigned short sA[128*32], sB[128*32];
  int tid = threadIdx.x;
  int row0 = blockIdx.x * 128, col0 = blockIdx.y * 128;
  f32x4 acc[4][4] = {};
  gemm_core(A, B, K, row0, col0, sA, sB, acc, tid);
  epilogue_store(acc, row0, col0, tid, ldc, act, Cf, Cb);
}

// ---------------- attention pass 1: per-chunk Esum, U = e^T V --------------
__global__ __launch_bounds__(256) void attn_pass1(
    const unsigned short* __restrict__ Kb, const unsigned short* __restrict__ Vb,
    unsigned short* __restrict__ U, float* __restrict__ Esum)
{
  __shared__ unsigned short se[128*128];  // e (bf16 bits), 32 KB
  __shared__ unsigned short sv[128*128];  // v chunk, 32 KB
  int tid = threadIdx.x;
  int bh = blockIdx.x >> 4, ch = blockIdx.x & 15;
  int b = bh >> 3, h = bh & 7;
  size_t rowbase = (size_t)(b*T_SEQ + ch*128)*HIDN + h*128;

#pragma unroll
  for (int i=0;i<8;i++){                  // K chunk -> e : 2048 uint4
    int u = tid + i*256; int t = u >> 4, kc = (u & 15)*8;
    float kv[8]; up8(&Kb[rowbase + (size_t)t*HIDN + kc], kv);
    ushort4 a, c;
    a.x=f2bu(__expf(kv[0])); a.y=f2bu(__expf(kv[1]));
    a.z=f2bu(__expf(kv[2])); a.w=f2bu(__expf(kv[3]));
    c.x=f2bu(__expf(kv[4])); c.y=f2bu(__expf(kv[5]));
    c.z=f2bu(__expf(kv[6])); c.w=f2bu(__expf(kv[7]));
    *(ushort4*)&se[t*128 + kc    ] = a;
    *(ushort4*)&se[t*128 + kc + 4] = c;
  }
#pragma unroll
  for (int i=0;i<8;i++){                  // V chunk: 2048 uint4
    int u = tid + i*256; int t = u >> 4, kc = (u & 15)*8;
    ((uint4*)sv)[u] = *(const uint4*)&Vb[rowbase + (size_t)t*HIDN + kc];
  }
  __syncthreads();

  if (tid < 128){                         // per-chunk column sums of e
    float s = 0.f;
#pragma unroll 8
    for (int t=0;t<128;t++) s += bu2f(se[t*128 + tid]);
    Esum[(size_t)blockIdx.x*128 + tid] = s;
  }

  int kg = tid >> 4, vg = tid & 15;
  int k0 = kg*8, v0 = vg*8;
  float uacc[8][8] = {};
  for (int s=0;s<128;s++){
    float ev[8], vv[8];
    up8(&se[s*128 + k0], ev);
    up8(&sv[s*128 + v0], vv);
#pragma unroll
    for (int i=0;i<8;i++)
#pragma unroll
      for (int j=0;j<8;j++) uacc[i][j] += ev[i]*vv[j];
  }
  unsigned short* Ub = U + (size_t)blockIdx.x*16384;
#pragma unroll
  for (int i=0;i<8;i++){
    ushort4 w0, w1;
    w0.x=f2bu(uacc[i][0]); w0.y=f2bu(uacc[i][1]); w0.z=f2bu(uacc[i][2]); w0.w=f2bu(uacc[i][3]);
    w1.x=f2bu(uacc[i][4]); w1.y=f2bu(uacc[i][5]); w1.z=f2bu(uacc[i][6]); w1.w=f2bu(uacc[i][7]);
    *(ushort4*)&Ub[(k0+i)*128 + v0    ] = w0;
    *(ushort4*)&Ub[(k0+i)*128 + v0 + 4] = w1;
  }
}

// ---------------- pass 2: exclusive prefix over chunks (in place) ----------
__global__ __launch_bounds__(256) void attn_pass2(
    unsigned short* __restrict__ U, float* __restrict__ Esum)
{
  int bh = blockIdx.x >> 4, sl = blockIdx.x & 15;
  int p = sl*1024 + threadIdx.x*4;        // element index within 16384
  float r0=0.f, r1=0.f, r2=0.f, r3=0.f;
  for (int c=0;c<16;c++){
    ushort4* ptr = (ushort4*)&U[(size_t)(bh*16 + c)*16384 + p];
    ushort4 t = *ptr;
    ushort4 w;
    w.x=f2bu(r0); w.y=f2bu(r1); w.z=f2bu(r2); w.w=f2bu(r3);
    *ptr = w;
    r0 += bu2f(t.x); r1 += bu2f(t.y); r2 += bu2f(t.z); r3 += bu2f(t.w);
  }
  if (sl == 0 && threadIdx.x < 128){
    float r = 0.f;
    for (int c=0;c<16;c++){
      float* q = &Esum[(size_t)(bh*16 + c)*128 + threadIdx.x];
      float t = *q; *q = r; r += t;
    }
  }
}

// ---------------- pass 3: o = qn@Cprev + causal(qn@e^T)@V ------------------
__global__ __launch_bounds__(512) void attn_pass3(
    const unsigned short* __restrict__ Kb, const unsigned short* __restrict__ Qb,
    const unsigned short* __restrict__ Vb, const unsigned short* __restrict__ U,
    const float* __restrict__ Esum, unsigned short* __restrict__ Oatt)
{
  __shared__ unsigned short sm0[128*128];  // e, later V
  __shared__ unsigned short sm1[128*128];  // qn, later P
  int tid = threadIdx.x;
  int bh = blockIdx.x >> 4, ch = blockIdx.x & 15;
  int b = bh >> 3, h = bh & 7;
  size_t rowbase = (size_t)(b*T_SEQ + ch*128)*HIDN + h*128;

#pragma unroll
  for (int i=0;i<4;i++){                   // Q chunk: 2048 uint4
    int u = tid + i*512; int t = u >> 4, kc = (u & 15)*8;
    ((uint4*)sm1)[u] = *(const uint4*)&Qb[rowbase + (size_t)t*HIDN + kc];
  }
#pragma unroll
  for (int i=0;i<4;i++){                   // K chunk -> e : 2048 uint4
    int u = tid + i*512; int t = u >> 4, kc = (u & 15)*8;
    float kv[8]; up8(&Kb[rowbase + (size_t)t*HIDN + kc], kv);
    ushort4 a, c;
    a.x=f2bu(__expf(kv[0])); a.y=f2bu(__expf(kv[1]));
    a.z=f2bu(__expf(kv[2])); a.w=f2bu(__expf(kv[3]));
    c.x=f2bu(__expf(kv[4])); c.y=f2bu(__expf(kv[5]));
    c.z=f2bu(__expf(kv[6])); c.w=f2bu(__expf(kv[7]));
    *(ushort4*)&sm0[t*128 + kc    ] = a;
    *(ushort4*)&sm0[t*128 + kc + 4] = c;
  }
  __syncthreads();

  if (tid < 128){                          // inclusive cumsum; qn = q*scale/E_t
    float run = Esum[(size_t)blockIdx.x*128 + tid];
#pragma unroll 8
    for (int s=0;s<128;s++){
      run += bu2f(sm0[s*128 + tid]);
      float q = bu2f(sm1[s*128 + tid]);
      sm1[s*128 + tid] = f2bu(q * SCALE / run);
    }
  }
  __syncthreads();

  int tg = tid >> 4, vg = tid & 15;
  int t0 = tg*4, v0 = vg*8;                // v0 doubles as s0 for scores
  float o[4][8] = {};

  // inter: o += qn @ Cprev (bf16 exclusive-prefix state from global)
  const unsigned short* Cprev = U + (size_t)blockIdx.x*16384;
  for (int ks=0; ks<16; ++ks){
    float a[4][8];
#pragma unroll
    for (int i=0;i<4;i++) up8(&sm1[(t0+i)*128 + ks*8], a[i]);
#pragma unroll
    for (int j=0;j<8;j++){
      int k = ks*8 + j;
      float c[8]; up8(&Cprev[(size_t)k*128 + v0], c);
#pragma unroll
      for (int i=0;i<4;i++){
#pragma unroll
        for (int n=0;n<8;n++) o[i][n] += a[i][j]*c[n];
      }
    }
  }

  // scores: P[t][s] = sum_k qn[t][k]*e[s][k]
  float p[4][8] = {};
  for (int ks=0; ks<16; ++ks){
    float a[4][8];
#pragma unroll
    for (int i=0;i<4;i++) up8(&sm1[(t0+i)*128 + ks*8], a[i]);
#pragma unroll
    for (int j=0;j<8;j++){
      float bb[8]; up8(&sm0[(v0+j)*128 + ks*8], bb);
#pragma unroll
      for (int i=0;i<4;i++){
        float s = p[i][j];
#pragma unroll
        for (int m=0;m<8;m++) s += a[i][m]*bb[m];
        p[i][j] = s;
      }
    }
  }
  __syncthreads();                         // everyone done reading sm0/sm1

  // write causal-masked P (bf16) into sm1; load V into sm0
#pragma unroll
  for (int i=0;i<4;i++){
    int t = t0 + i;
    ushort4 w0, w1;
    w0.x = f2bu((v0+0<=t)?p[i][0]:0.f); w0.y = f2bu((v0+1<=t)?p[i][1]:0.f);
    w0.z = f2bu((v0+2<=t)?p[i][2]:0.f); w0.w = f2bu((v0+3<=t)?p[i][3]:0.f);
    w1.x = f2bu((v0+4<=t)?p[i][4]:0.f); w1.y = f2bu((v0+5<=t)?p[i][5]:0.f);
    w1.z = f2bu((v0+6<=t)?p[i][6]:0.f); w1.w = f2bu((v0+7<=t)?p[i][7]:0.f);
    *(ushort4*)&sm1[t*128 + v0    ] = w0;
    *(ushort4*)&sm1[t*128 + v0 + 4] = w1;
  }
#pragma unroll
  for (int i=0;i<4;i++){
    int u = tid + i*512; int t = u >> 4, kc = (u & 15)*8;
    ((uint4*)sm0)[u] = *(const uint4*)&Vb[rowbase + (size_t)t*HIDN + kc];
  }
  __syncthreads();

  // intra: o += P @ V
  for (int ss=0; ss<16; ++ss){
    float a[4][8];
#pragma unroll
    for (int i=0;i<4;i++) up8(&sm1[(t0+i)*128 + ss*8], a[i]);
#pragma unroll
    for (int m=0;m<8;m++){
      float bb[8]; up8(&sm0[(ss*8+m)*128 + v0], bb);
#pragma unroll
      for (int i=0;i<4;i++){
#pragma unroll
        for (int n=0;n<8;n++) o[i][n] += a[i][m]*bb[n];
      }
    }
  }

#pragma unroll
  for (int i=0;i<4;i++){
    ushort4 w0, w1;
    w0.x=f2bu(o[i][0]); w0.y=f2bu(o[i][1]); w0.z=f2bu(o[i][2]); w0.w=f2bu(o[i][3]);
    w1.x=f2bu(o[i][4]); w1.y=f2bu(o[i][5]); w1.z=f2bu(o[i][6]); w1.w=f2bu(o[i][7]);
    *(ushort4*)&Oatt[rowbase + (size_t)(t0+i)*HIDN + v0    ] = w0;
    *(ushort4*)&Oatt[rowbase + (size_t)(t0+i)*HIDN + v0 + 4] = w1;
  }
}

// ---------------- RMSNorm * gnw * swish(gate) -> bf16 ----------------------
__global__ __launch_bounds__(256) void norm_gate(
    const unsigned short* __restrict__ Oatt, const unsigned short* __restrict__ Gt,
    const unsigned short* __restrict__ gnw, unsigned short* __restrict__ Onorm)
{
  int row = blockIdx.x, tid = threadIdx.x;
  ushort4 o4 = *(const ushort4*)&Oatt[(size_t)row*HIDN + tid*4];
  float ox = bu2f(o4.x), oy = bu2f(o4.y), oz = bu2f(o4.z), ow = bu2f(o4.w);
  float ss = ox*ox + oy*oy + oz*oz + ow*ow;
#pragma unroll
  for (int off=32; off>0; off>>=1) ss += __shfl_down(ss, off, 64);
  __shared__ float red[4];
  if ((tid & 63) == 0) red[tid>>6] = ss;
  __syncthreads();
  float rstd = rsqrtf((red[0]+red[1]+red[2]+red[3]) * (1.f/1024.f) + 1e-5f);
  ushort4 g4 = *(const ushort4*)&Gt[(size_t)row*HIDN + tid*4];   // swish(gate)
  ushort4 w4 = *(const ushort4*)&gnw[tid*4];
  ushort4 r4;
  r4.x = f2bu(ox * rstd * bu2f(w4.x) * bu2f(g4.x));
  r4.y = f2bu(oy * rstd * bu2f(w4.y) * bu2f(g4.y));
  r4.z = f2bu(oz * rstd * bu2f(w4.z) * bu2f(g4.z));
  r4.w = f2bu(ow * rstd * bu2f(w4.w) * bu2f(g4.w));
  *(ushort4*)&Onorm[(size_t)row*HIDN + tid*4] = r4;
}

// ---------------- launch ----------------
extern "C" void kernel_launch(void* const* d_in, const int* in_sizes, int n_in,
                              void* d_out, int out_size, void* d_ws, size_t ws_size,
                              hipStream_t stream) {
  unsigned short* wsS = (unsigned short*)d_ws;     // ~66 MiB used
  int* flag = (int*)d_ws;                          // shorts [0,8)

  // canonical bf16 inputs
  unsigned short* Xc   = wsS + 8;          // 4,194,304
  unsigned short* Wqc  = wsS + 4194312;    // 1,048,576
  unsigned short* Wkc  = wsS + 5242888;    // 1,048,576
  unsigned short* Wvc  = wsS + 6291464;    // 1,048,576
  unsigned short* Wg1c = wsS + 7340040;    //   131,072
  unsigned short* Wg2c = wsS + 7471112;    //   131,072
  unsigned short* gnwc = wsS + 7602184;    //     1,024
  unsigned short* Woc  = wsS + 7603208;    // 1,048,576
  // work buffers
  unsigned short* Qb   = wsS + 8651784;    // 4,194,304
  unsigned short* Kb   = wsS + 12846088;   // 4,194,304
  unsigned short* Vb   = wsS + 17040392;   // 4,194,304
  unsigned short* G1b  = wsS + 21234696;   //   524,288
  unsigned short* Gt   = wsS + 21758984;   // 4,194,304
  unsigned short* Ub   = wsS + 25953288;   // 4,194,304
  unsigned short* Oattb= wsS + 30147592;   // 4,194,304
  float*          Esum = (float*)(wsS + 34341896);  // 32,768 floats
  unsigned short* Onorm = Qb;              // Q dead after pass3

  detect_dtype<<<1, 256, 0, stream>>>((const float*)d_in[0], flag);
  convert_input<<<2048, 256, 0, stream>>>(d_in[0], Xc,   4194304, flag);
  convert_input<<<1024, 256, 0, stream>>>(d_in[1], Wqc,  1048576, flag);
  convert_input<<<1024, 256, 0, stream>>>(d_in[2], Wkc,  1048576, flag);
  convert_input<<<1024, 256, 0, stream>>>(d_in[3], Wvc,  1048576, flag);
  convert_input<<< 128, 256, 0, stream>>>(d_in[4], Wg1c,  131072, flag);
  convert_input<<< 128, 256, 0, stream>>>(d_in[5], Wg2c,  131072, flag);
  convert_input<<<   4, 256, 0, stream>>>(d_in[6], gnwc,    1024, flag);
  convert_input<<<1024, 256, 0, stream>>>(d_in[7], Woc,  1048576, flag);

  proj_kernel<<<dim3(32,25), 256, 0, stream>>>(Xc, Wqc, Wkc, Wvc, Wg1c, Qb, Kb, Vb, G1b);
  gemm_bt   <<<dim3(32,8),  256, 0, stream>>>(G1b, Wg2c, 128, HIDN, 1, nullptr, Gt);
  attn_pass1<<<256, 256, 0, stream>>>(Kb, Vb, Ub, Esum);
  attn_pass2<<<256, 256, 0, stream>>>(Ub, Esum);
  attn_pass3<<<256, 512, 0, stream>>>(Kb, Qb, Vb, Ub, Esum, Oattb);
  norm_gate <<<4096, 256, 0, stream>>>(Oattb, Gt, gnwc, Onorm);
  // FINAL GEMM: fp32 output (reference returns float32 -> d_out is float*)
  gemm_bt   <<<dim3(32,8),  256, 0, stream>>>(Onorm, Woc, HIDN, HIDN, 0,
                                              (float*)d_out, nullptr);
}

// Round 5
// 280.047 us; speedup vs baseline: 1.6048x; 1.6048x over previous
//
#include <hip/hip_runtime.h>
#include <hip/hip_bf16.h>
#include <stdint.h>

// LightNet attention fwd. B=2, T=2048, HID=1024, H=8, DK=DV=128, LR=128.
// Contract (established R1-R4): inputs fp32, output fp32.
//
// Math: z=logcumsumexp(k) telescopes the gated scan to
//   o_t[v] = scale * sum_k (q_t[k]/E_t[k]) * sum_{s<=t} e_s[k] v_s[v],
// e=exp(k), E=cumsum(e). Chunked Tc=128: pass1 per-chunk Esum/U=e^T V;
// pass2 exclusive chunk prefix; pass3 intra(causal)+inter.
// GEMMs: bf16 MFMA 128x128 tile, BK=32, global_load_lds width-16 staging
// (m97 structure), LDS-staged coalesced bf16 epilogue (kills the 8x
// write amplification R4's WRITE_SIZE=204MB exposed).

typedef short short8 __attribute__((ext_vector_type(8)));
typedef float f32x4 __attribute__((ext_vector_type(4)));

#define T_SEQ 2048
#define HIDN  1024
#define SCALE 0.08838834764831845f   // 128^-0.5

// ---------------- bf16 bit helpers ----------------
__device__ __forceinline__ float blo(unsigned int u){
  union{unsigned int i; float f;} v; v.i = u << 16; return v.f;
}
__device__ __forceinline__ float bhi(unsigned int u){
  union{unsigned int i; float f;} v; v.i = u & 0xffff0000u; return v.f;
}
__device__ __forceinline__ float bu2f(unsigned short u){
  union{unsigned int i; float f;} v; v.i = ((unsigned int)u) << 16; return v.f;
}
__device__ __forceinline__ unsigned short f2bu(float f){
  union{float f; unsigned int i;} v; v.f = f;
  unsigned int x = v.i;
  x += 0x7fffu + ((x >> 16) & 1u);     // RNE
  return (unsigned short)(x >> 16);
}
__device__ __forceinline__ void up8(const unsigned short* p, float* f){
  uint4 v = *(const uint4*)p;
  f[0]=blo(v.x); f[1]=bhi(v.x); f[2]=blo(v.y); f[3]=bhi(v.y);
  f[4]=blo(v.z); f[5]=bhi(v.z); f[6]=blo(v.w); f[7]=bhi(v.w);
}
__device__ __forceinline__ void async16(const void* g, void* l){
  __builtin_amdgcn_global_load_lds(
      (const __attribute__((address_space(1))) unsigned int*)g,
      (__attribute__((address_space(3))) unsigned int*)l, 16, 0, 0);
}

// ---------------- fused input cast: all 8 fp32 tensors -> bf16 ------------
// quad counts: X 1048576 | Wq/Wk/Wv/Wo 262144 ea | Wg1/Wg2 32768 ea | gnw 256
// total 2,162,944 quads = 8449 blocks x 256 exactly.
__global__ __launch_bounds__(256) void convert_all(
    const float* __restrict__ X,  const float* __restrict__ Wq,
    const float* __restrict__ Wk, const float* __restrict__ Wv,
    const float* __restrict__ Wg1,const float* __restrict__ Wg2,
    const float* __restrict__ gnw,const float* __restrict__ Wo,
    unsigned short* __restrict__ base)
{
  int q = blockIdx.x * 256 + threadIdx.x;
  const float* src; unsigned short* dst; int rel = q;
  if (rel < 1048576)            { src = X;   dst = base;            }
  else if ((rel -= 1048576) < 262144) { src = Wq;  dst = base + 4194304; }
  else if ((rel -=  262144) < 262144) { src = Wk;  dst = base + 5242880; }
  else if ((rel -=  262144) < 262144) { src = Wv;  dst = base + 6291456; }
  else if ((rel -=  262144) < 262144) { src = Wo;  dst = base + 7340032; }
  else if ((rel -=  262144) <  32768) { src = Wg1; dst = base + 8388608; }
  else if ((rel -=   32768) <  32768) { src = Wg2; dst = base + 8519680; }
  else   { rel -= 32768;                src = gnw; dst = base + 8650752; }
  float4 v = ((const float4*)src)[rel];
  ushort4 o; o.x=f2bu(v.x); o.y=f2bu(v.y); o.z=f2bu(v.z); o.w=f2bu(v.w);
  ((ushort4*)dst)[rel] = o;
}

// ---------------- MFMA GEMM core: C(128x128) = A @ B^T, bf16, fp32 acc ----
// A [M][K], B [N][K] bf16 bits. 256 threads. global_load_lds width-16:
// per-lane global addr, wave-uniform LDS base (HW lands lane l at base+16*l).
__device__ __forceinline__ void gemm_core(
    const unsigned short* __restrict__ A, const unsigned short* __restrict__ B,
    int K, int row0, int col0,
    unsigned short* sA, unsigned short* sB, f32x4 acc[4][4], int tid)
{
  const int lane = tid & 63;
  const int wm = (tid >> 6) & 1, wn = tid >> 7;
  const int wb = tid & 192;                // wave-uniform chunk base
  for (int k0 = 0; k0 < K; k0 += 32){
    __syncthreads();                       // prev iter's LDS reads done
#pragma unroll
    for (int r = 0; r < 2; ++r){
      int idx  = r*256 + tid;              // 512 chunks of 16B per tile
      int mrow = idx >> 2, kc = (idx & 3) * 8;
      async16(A + (size_t)(row0 + mrow)*K + k0 + kc, sA + (size_t)(r*256 + wb)*8);
      async16(B + (size_t)(col0 + mrow)*K + k0 + kc, sB + (size_t)(r*256 + wb)*8);
    }
    __syncthreads();                       // drains vmcnt before barrier
    short8 av[4], bv[4];
#pragma unroll
    for (int i=0;i<4;i++)
      av[i] = *(const short8*)(sA + (size_t)(wm*64 + i*16 + (lane&15))*32 + (lane>>4)*8);
#pragma unroll
    for (int j=0;j<4;j++)
      bv[j] = *(const short8*)(sB + (size_t)(wn*64 + j*16 + (lane&15))*32 + (lane>>4)*8);
#pragma unroll
    for (int i=0;i<4;i++)
#pragma unroll
      for (int j=0;j<4;j++)
        acc[i][j] = __builtin_amdgcn_mfma_f32_16x16x32_bf16(av[i], bv[j], acc[i][j], 0, 0, 0);
  }
}

// bf16 epilogue via LDS: 4 passes of 32 rows; coalesced b128 copy-out
// (full-line HBM writes). sC = 32x128 shorts (8 KB, aliases sA).
__device__ __forceinline__ void epilogue_lds(
    f32x4 acc[4][4], int row0, int col0, int tid, int ldc, int act,
    unsigned short* __restrict__ Cb, unsigned short* sC)
{
  const int lane = tid & 63;
  const int wm = (tid >> 6) & 1, wn = tid >> 7;
#pragma unroll
  for (int p=0;p<4;p++){
    __syncthreads();                       // sC free (k-loop reads / prev copy)
    if (wm == (p>>1)){
#pragma unroll
      for (int ii=0; ii<2; ii++){
        int i = (p&1)*2 + ii;
        int lr = i*16 + ((lane>>4)<<2) - (p&1)*32;   // local row in [0,32)
#pragma unroll
        for (int j=0;j<4;j++){
          int col = wn*64 + j*16 + (lane&15);
#pragma unroll
          for (int r=0;r<4;r++){
            float v = acc[i][j][r];
            if (act) v = v / (1.f + __expf(-v));
            sC[(lr+r)*128 + col] = f2bu(v);
          }
        }
      }
    }
    __syncthreads();
#pragma unroll
    for (int c = tid; c < 512; c += 256){  // 32 rows x 256B
      int rr = c >> 4, off = (c & 15)*8;
      *(uint4*)&Cb[(size_t)(row0 + p*32 + rr)*ldc + col0 + off] =
          *(const uint4*)&sC[rr*128 + off];
    }
  }
}

// fp32 direct epilogue (64B full-line segments — no amplification).
__device__ __forceinline__ void epilogue_f32(
    f32x4 acc[4][4], int row0, int col0, int tid, int ldc,
    float* __restrict__ Cf)
{
  const int lane = tid & 63;
  const int wm = (tid >> 6) & 1, wn = tid >> 7;
#pragma unroll
  for (int i=0;i<4;i++){
    int rbase = row0 + wm*64 + i*16 + ((lane>>4)<<2);
#pragma unroll
    for (int j=0;j<4;j++){
      int col = col0 + wn*64 + j*16 + (lane&15);
#pragma unroll
      for (int r=0;r<4;r++)
        Cf[(size_t)(rbase + r)*ldc + col] = acc[i][j][r];
    }
  }
}

// Fused QKV+G1 projection. grid (32, 25): y<8 ->Q(silu), <16 ->K, <24 ->V,
// ==24 ->G1 (ldc=128).
__global__ __launch_bounds__(256, 2) void proj_kernel(
    const unsigned short* __restrict__ X,
    const unsigned short* __restrict__ Wq, const unsigned short* __restrict__ Wk,
    const unsigned short* __restrict__ Wv, const unsigned short* __restrict__ Wg1,
    unsigned short* __restrict__ Qb, unsigned short* __restrict__ Kb,
    unsigned short* __restrict__ Vb, unsigned short* __restrict__ G1b)
{
  __shared__ unsigned short sA[128*32], sB[128*32];
  int tid = threadIdx.x;
  int which = blockIdx.y >> 3;
  const unsigned short* Bp = (which==0)?Wq:(which==1)?Wk:(which==2)?Wv:Wg1;
  int row0 = blockIdx.x * 128;
  int col0 = (which==3) ? 0 : (blockIdx.y & 7) * 128;
  f32x4 acc[4][4] = {};
  gemm_core(X, Bp, HIDN, row0, col0, sA, sB, acc, tid);
  if      (which==0) epilogue_lds(acc,row0,col0,tid,HIDN,1,Qb, sA);
  else if (which==1) epilogue_lds(acc,row0,col0,tid,HIDN,0,Kb, sA);
  else if (which==2) epilogue_lds(acc,row0,col0,tid,HIDN,0,Vb, sA);
  else               epilogue_lds(acc,row0,col0,tid,128 ,0,G1b,sA);
}

// Generic A@B^T. Cb nonnull -> bf16 LDS epilogue (w/ optional swish);
// else fp32 direct store (final output).
__global__ __launch_bounds__(256, 2) void gemm_bt(
    const unsigned short* __restrict__ A, const unsigned short* __restrict__ B,
    int K, int ldc, int act, float* __restrict__ Cf,
    unsigned short* __restrict__ Cb)
{
  __shared__ unsigned short sA[128*32], sB[128*32];
  int tid = threadIdx.x;
  int row0 = blockIdx.x * 128, col0 = blockIdx.y * 128;
  f32x4 acc[4][4] = {};
  gemm_core(A, B, K, row0, col0, sA, sB, acc, tid);
  if (Cb) epilogue_lds(acc, row0, col0, tid, ldc, act, Cb, sA);
  else    epilogue_f32(acc, row0, col0, tid, ldc, Cf);
}

// ---------------- attention pass 1: per-chunk Esum, U = e^T V --------------
__global__ __launch_bounds__(256) void attn_pass1(
    const unsigned short* __restrict__ Kb, const unsigned short* __restrict__ Vb,
    unsigned short* __restrict__ U, float* __restrict__ Esum)
{
  __shared__ unsigned short se[128*128];  // e (bf16 bits), 32 KB
  __shared__ unsigned short sv[128*128];  // v chunk, 32 KB
  int tid = threadIdx.x;
  int bh = blockIdx.x >> 4, ch = blockIdx.x & 15;
  int b = bh >> 3, h = bh & 7;
  size_t rowbase = (size_t)(b*T_SEQ + ch*128)*HIDN + h*128;

#pragma unroll
  for (int i=0;i<8;i++){                  // K chunk -> e : 2048 uint4
    int u = tid + i*256; int t = u >> 4, kc = (u & 15)*8;
    float kv[8]; up8(&Kb[rowbase + (size_t)t*HIDN + kc], kv);
    ushort4 a, c;
    a.x=f2bu(__expf(kv[0])); a.y=f2bu(__expf(kv[1]));
    a.z=f2bu(__expf(kv[2])); a.w=f2bu(__expf(kv[3]));
    c.x=f2bu(__expf(kv[4])); c.y=f2bu(__expf(kv[5]));
    c.z=f2bu(__expf(kv[6])); c.w=f2bu(__expf(kv[7]));
    *(ushort4*)&se[t*128 + kc    ] = a;
    *(ushort4*)&se[t*128 + kc + 4] = c;
  }
#pragma unroll
  for (int i=0;i<8;i++){                  // V chunk: 2048 uint4
    int u = tid + i*256; int t = u >> 4, kc = (u & 15)*8;
    ((uint4*)sv)[u] = *(const uint4*)&Vb[rowbase + (size_t)t*HIDN + kc];
  }
  __syncthreads();

  if (tid < 128){                         // per-chunk column sums of e
    float s = 0.f;
#pragma unroll 8
    for (int t=0;t<128;t++) s += bu2f(se[t*128 + tid]);
    Esum[(size_t)blockIdx.x*128 + tid] = s;
  }

  int kg = tid >> 4, vg = tid & 15;
  int k0 = kg*8, v0 = vg*8;
  float uacc[8][8] = {};
  for (int s=0;s<128;s++){
    float ev[8], vv[8];
    up8(&se[s*128 + k0], ev);
    up8(&sv[s*128 + v0], vv);
#pragma unroll
    for (int i=0;i<8;i++)
#pragma unroll
      for (int j=0;j<8;j++) uacc[i][j] += ev[i]*vv[j];
  }
  unsigned short* Ub = U + (size_t)blockIdx.x*16384;
#pragma unroll
  for (int i=0;i<8;i++){
    ushort4 w0, w1;
    w0.x=f2bu(uacc[i][0]); w0.y=f2bu(uacc[i][1]); w0.z=f2bu(uacc[i][2]); w0.w=f2bu(uacc[i][3]);
    w1.x=f2bu(uacc[i][4]); w1.y=f2bu(uacc[i][5]); w1.z=f2bu(uacc[i][6]); w1.w=f2bu(uacc[i][7]);
    *(ushort4*)&Ub[(k0+i)*128 + v0    ] = w0;
    *(ushort4*)&Ub[(k0+i)*128 + v0 + 4] = w1;
  }
}

// ---------------- pass 2: exclusive prefix over chunks (in place) ----------
__global__ __launch_bounds__(256) void attn_pass2(
    unsigned short* __restrict__ U, float* __restrict__ Esum)
{
  int bh = blockIdx.x >> 4, sl = blockIdx.x & 15;
  int p = sl*1024 + threadIdx.x*4;        // element index within 16384
  float r0=0.f, r1=0.f, r2=0.f, r3=0.f;
  for (int c=0;c<16;c++){
    ushort4* ptr = (ushort4*)&U[(size_t)(bh*16 + c)*16384 + p];
    ushort4 t = *ptr;
    ushort4 w;
    w.x=f2bu(r0); w.y=f2bu(r1); w.z=f2bu(r2); w.w=f2bu(r3);
    *ptr = w;
    r0 += bu2f(t.x); r1 += bu2f(t.y); r2 += bu2f(t.z); r3 += bu2f(t.w);
  }
  if (sl == 0 && threadIdx.x < 128){
    float r = 0.f;
    for (int c=0;c<16;c++){
      float* q = &Esum[(size_t)(bh*16 + c)*128 + threadIdx.x];
      float t = *q; *q = r; r += t;
    }
  }
}

// ---------------- pass 3: o = qn@Cprev + causal(qn@e^T)@V ------------------
__global__ __launch_bounds__(512) void attn_pass3(
    const unsigned short* __restrict__ Kb, const unsigned short* __restrict__ Qb,
    const unsigned short* __restrict__ Vb, const unsigned short* __restrict__ U,
    const float* __restrict__ Esum, unsigned short* __restrict__ Oatt)
{
  __shared__ unsigned short sm0[128*128];  // e, later V
  __shared__ unsigned short sm1[128*128];  // qn, later P
  int tid = threadIdx.x;
  int bh = blockIdx.x >> 4, ch = blockIdx.x & 15;
  int b = bh >> 3, h = bh & 7;
  size_t rowbase = (size_t)(b*T_SEQ + ch*128)*HIDN + h*128;

#pragma unroll
  for (int i=0;i<4;i++){                   // Q chunk: 2048 uint4
    int u = tid + i*512; int t = u >> 4, kc = (u & 15)*8;
    ((uint4*)sm1)[u] = *(const uint4*)&Qb[rowbase + (size_t)t*HIDN + kc];
  }
#pragma unroll
  for (int i=0;i<4;i++){                   // K chunk -> e : 2048 uint4
    int u = tid + i*512; int t = u >> 4, kc = (u & 15)*8;
    float kv[8]; up8(&Kb[rowbase + (size_t)t*HIDN + kc], kv);
    ushort4 a, c;
    a.x=f2bu(__expf(kv[0])); a.y=f2bu(__expf(kv[1]));
    a.z=f2bu(__expf(kv[2])); a.w=f2bu(__expf(kv[3]));
    c.x=f2bu(__expf(kv[4])); c.y=f2bu(__expf(kv[5]));
    c.z=f2bu(__expf(kv[6])); c.w=f2bu(__expf(kv[7]));
    *(ushort4*)&sm0[t*128 + kc    ] = a;
    *(ushort4*)&sm0[t*128 + kc + 4] = c;
  }
  __syncthreads();

  if (tid < 128){                          // inclusive cumsum; qn = q*scale/E_t
    float run = Esum[(size_t)blockIdx.x*128 + tid];
#pragma unroll 8
    for (int s=0;s<128;s++){
      run += bu2f(sm0[s*128 + tid]);
      float q = bu2f(sm1[s*128 + tid]);
      sm1[s*128 + tid] = f2bu(q * SCALE / run);
    }
  }
  __syncthreads();

  int tg = tid >> 4, vg = tid & 15;
  int t0 = tg*4, v0 = vg*8;                // v0 doubles as s0 for scores
  float o[4][8] = {};

  // inter: o += qn @ Cprev (bf16 exclusive-prefix state from global)
  const unsigned short* Cprev = U + (size_t)blockIdx.x*16384;
  for (int ks=0; ks<16; ++ks){
    float a[4][8];
#pragma unroll
    for (int i=0;i<4;i++) up8(&sm1[(t0+i)*128 + ks*8], a[i]);
#pragma unroll
    for (int j=0;j<8;j++){
      int k = ks*8 + j;
      float c[8]; up8(&Cprev[(size_t)k*128 + v0], c);
#pragma unroll
      for (int i=0;i<4;i++){
#pragma unroll
        for (int n=0;n<8;n++) o[i][n] += a[i][j]*c[n];
      }
    }
  }

  // scores: P[t][s] = sum_k qn[t][k]*e[s][k]
  float p[4][8] = {};
  for (int ks=0; ks<16; ++ks){
    float a[4][8];
#pragma unroll
    for (int i=0;i<4;i++) up8(&sm1[(t0+i)*128 + ks*8], a[i]);
#pragma unroll
    for (int j=0;j<8;j++){
      float bb[8]; up8(&sm0[(v0+j)*128 + ks*8], bb);
#pragma unroll
      for (int i=0;i<4;i++){
        float s = p[i][j];
#pragma unroll
        for (int m=0;m<8;m++) s += a[i][m]*bb[m];
        p[i][j] = s;
      }
    }
  }
  __syncthreads();                         // everyone done reading sm0/sm1

  // write causal-masked P (bf16) into sm1; load V into sm0
#pragma unroll
  for (int i=0;i<4;i++){
    int t = t0 + i;
    ushort4 w0, w1;
    w0.x = f2bu((v0+0<=t)?p[i][0]:0.f); w0.y = f2bu((v0+1<=t)?p[i][1]:0.f);
    w0.z = f2bu((v0+2<=t)?p[i][2]:0.f); w0.w = f2bu((v0+3<=t)?p[i][3]:0.f);
    w1.x = f2bu((v0+4<=t)?p[i][4]:0.f); w1.y = f2bu((v0+5<=t)?p[i][5]:0.f);
    w1.z = f2bu((v0+6<=t)?p[i][6]:0.f); w1.w = f2bu((v0+7<=t)?p[i][7]:0.f);
    *(ushort4*)&sm1[t*128 + v0    ] = w0;
    *(ushort4*)&sm1[t*128 + v0 + 4] = w1;
  }
#pragma unroll
  for (int i=0;i<4;i++){
    int u = tid + i*512; int t = u >> 4, kc = (u & 15)*8;
    ((uint4*)sm0)[u] = *(const uint4*)&Vb[rowbase + (size_t)t*HIDN + kc];
  }
  __syncthreads();

  // intra: o += P @ V
  for (int ss=0; ss<16; ++ss){
    float a[4][8];
#pragma unroll
    for (int i=0;i<4;i++) up8(&sm1[(t0+i)*128 + ss*8], a[i]);
#pragma unroll
    for (int m=0;m<8;m++){
      float bb[8]; up8(&sm0[(ss*8+m)*128 + v0], bb);
#pragma unroll
      for (int i=0;i<4;i++){
#pragma unroll
        for (int n=0;n<8;n++) o[i][n] += a[i][m]*bb[n];
      }
    }
  }

#pragma unroll
  for (int i=0;i<4;i++){
    ushort4 w0, w1;
    w0.x=f2bu(o[i][0]); w0.y=f2bu(o[i][1]); w0.z=f2bu(o[i][2]); w0.w=f2bu(o[i][3]);
    w1.x=f2bu(o[i][4]); w1.y=f2bu(o[i][5]); w1.z=f2bu(o[i][6]); w1.w=f2bu(o[i][7]);
    *(ushort4*)&Oatt[rowbase + (size_t)(t0+i)*HIDN + v0    ] = w0;
    *(ushort4*)&Oatt[rowbase + (size_t)(t0+i)*HIDN + v0 + 4] = w1;
  }
}

// ---------------- RMSNorm * gnw * swish(gate) -> bf16 ----------------------
__global__ __launch_bounds__(256) void norm_gate(
    const unsigned short* __restrict__ Oatt, const unsigned short* __restrict__ Gt,
    const unsigned short* __restrict__ gnw, unsigned short* __restrict__ Onorm)
{
  int row = blockIdx.x, tid = threadIdx.x;
  ushort4 o4 = *(const ushort4*)&Oatt[(size_t)row*HIDN + tid*4];
  float ox = bu2f(o4.x), oy = bu2f(o4.y), oz = bu2f(o4.z), ow = bu2f(o4.w);
  float ss = ox*ox + oy*oy + oz*oz + ow*ow;
#pragma unroll
  for (int off=32; off>0; off>>=1) ss += __shfl_down(ss, off, 64);
  __shared__ float red[4];
  if ((tid & 63) == 0) red[tid>>6] = ss;
  __syncthreads();
  float rstd = rsqrtf((red[0]+red[1]+red[2]+red[3]) * (1.f/1024.f) + 1e-5f);
  ushort4 g4 = *(const ushort4*)&Gt[(size_t)row*HIDN + tid*4];   // swish(gate)
  ushort4 w4 = *(const ushort4*)&gnw[tid*4];
  ushort4 r4;
  r4.x = f2bu(ox * rstd * bu2f(w4.x) * bu2f(g4.x));
  r4.y = f2bu(oy * rstd * bu2f(w4.y) * bu2f(g4.y));
  r4.z = f2bu(oz * rstd * bu2f(w4.z) * bu2f(g4.z));
  r4.w = f2bu(ow * rstd * bu2f(w4.w) * bu2f(g4.w));
  *(ushort4*)&Onorm[(size_t)row*HIDN + tid*4] = r4;
}

// ---------------- launch ----------------
extern "C" void kernel_launch(void* const* d_in, const int* in_sizes, int n_in,
                              void* d_out, int out_size, void* d_ws, size_t ws_size,
                              hipStream_t stream) {
  unsigned short* wsS = (unsigned short*)d_ws;     // ~69 MiB used

  // canonical bf16 inputs (offsets match convert_all routing table)
  unsigned short* Xc   = wsS;              // 4,194,304
  unsigned short* Wqc  = wsS + 4194304;    // 1,048,576
  unsigned short* Wkc  = wsS + 5242880;    // 1,048,576
  unsigned short* Wvc  = wsS + 6291456;    // 1,048,576
  unsigned short* Woc  = wsS + 7340032;    // 1,048,576
  unsigned short* Wg1c = wsS + 8388608;    //   131,072
  unsigned short* Wg2c = wsS + 8519680;    //   131,072
  unsigned short* gnwc = wsS + 8650752;    //     1,024
  // work buffers
  unsigned short* Qb   = wsS + 8651776;    // 4,194,304
  unsigned short* Kb   = wsS + 12846080;   // 4,194,304
  unsigned short* Vb   = wsS + 17040384;   // 4,194,304
  unsigned short* G1b  = wsS + 21234688;   //   524,288
  unsigned short* Gt   = wsS + 21758976;   // 4,194,304
  unsigned short* Ub   = wsS + 25953280;   // 4,194,304
  unsigned short* Oattb= wsS + 30147584;   // 4,194,304
  float*          Esum = (float*)(wsS + 34341888);  // 32,768 floats
  unsigned short* Onorm = Qb;              // Q dead after pass3

  convert_all<<<8449, 256, 0, stream>>>(
      (const float*)d_in[0], (const float*)d_in[1], (const float*)d_in[2],
      (const float*)d_in[3], (const float*)d_in[4], (const float*)d_in[5],
      (const float*)d_in[6], (const float*)d_in[7], wsS);

  proj_kernel<<<dim3(32,25), 256, 0, stream>>>(Xc, Wqc, Wkc, Wvc, Wg1c, Qb, Kb, Vb, G1b);
  gemm_bt   <<<dim3(32,8),  256, 0, stream>>>(G1b, Wg2c, 128, HIDN, 1, nullptr, Gt);
  attn_pass1<<<256, 256, 0, stream>>>(Kb, Vb, Ub, Esum);
  attn_pass2<<<256, 256, 0, stream>>>(Ub, Esum);
  attn_pass3<<<256, 512, 0, stream>>>(Kb, Qb, Vb, Ub, Esum, Oattb);
  norm_gate <<<4096, 256, 0, stream>>>(Oattb, Gt, gnwc, Onorm);
  // FINAL GEMM: fp32 output (d_out is float*)
  gemm_bt   <<<dim3(32,8),  256, 0, stream>>>(Onorm, Woc, HIDN, HIDN, 0,
                                              (float*)d_out, nullptr);
}

// Round 6
// 223.490 us; speedup vs baseline: 2.0110x; 1.2531x over previous
//
#include <hip/hip_runtime.h>
#include <hip/hip_bf16.h>
#include <stdint.h>

// LightNet attention fwd. B=2, T=2048, HID=1024, H=8, DK=DV=128, LR=128.
// Contract (established R1-R4): inputs fp32, output fp32.
//
// Math: z=logcumsumexp(k) telescopes the gated scan to
//   o_t[v] = scale * sum_k (q_t[k]/E_t[k]) * sum_{s<=t} e_s[k] v_s[v],
// e=exp(k), E=cumsum(e). Chunked Tc=128: pass1 per-chunk Esum/Ut=(e^T V)^T;
// pass2 exclusive chunk prefix; pass3 (MFMA) intra(causal)+inter.
// GEMMs: bf16 MFMA 128x128 tile, BK=32, global_load_lds width-16 staging,
// LDS-staged coalesced bf16 epilogue.

typedef short short8 __attribute__((ext_vector_type(8)));
typedef float f32x4 __attribute__((ext_vector_type(4)));

#define T_SEQ 2048
#define HIDN  1024
#define SCALE 0.08838834764831845f   // 128^-0.5
#define LDSP  136                    // padded LDS row stride (shorts) for pass3

// ---------------- bf16 bit helpers ----------------
__device__ __forceinline__ float blo(unsigned int u){
  union{unsigned int i; float f;} v; v.i = u << 16; return v.f;
}
__device__ __forceinline__ float bhi(unsigned int u){
  union{unsigned int i; float f;} v; v.i = u & 0xffff0000u; return v.f;
}
__device__ __forceinline__ float bu2f(unsigned short u){
  union{unsigned int i; float f;} v; v.i = ((unsigned int)u) << 16; return v.f;
}
__device__ __forceinline__ unsigned short f2bu(float f){
  union{float f; unsigned int i;} v; v.f = f;
  unsigned int x = v.i;
  x += 0x7fffu + ((x >> 16) & 1u);     // RNE
  return (unsigned short)(x >> 16);
}
__device__ __forceinline__ void up8(const unsigned short* p, float* f){
  uint4 v = *(const uint4*)p;
  f[0]=blo(v.x); f[1]=bhi(v.x); f[2]=blo(v.y); f[3]=bhi(v.y);
  f[4]=blo(v.z); f[5]=bhi(v.z); f[6]=blo(v.w); f[7]=bhi(v.w);
}
__device__ __forceinline__ void async16(const void* g, void* l){
  __builtin_amdgcn_global_load_lds(
      (const __attribute__((address_space(1))) unsigned int*)g,
      (__attribute__((address_space(3))) unsigned int*)l, 16, 0, 0);
}

// ---------------- fused input cast: all 8 fp32 tensors -> bf16 ------------
__global__ __launch_bounds__(256) void convert_all(
    const float* __restrict__ X,  const float* __restrict__ Wq,
    const float* __restrict__ Wk, const float* __restrict__ Wv,
    const float* __restrict__ Wg1,const float* __restrict__ Wg2,
    const float* __restrict__ gnw,const float* __restrict__ Wo,
    unsigned short* __restrict__ base)
{
  int q = blockIdx.x * 256 + threadIdx.x;
  const float* src; unsigned short* dst; int rel = q;
  if (rel < 1048576)            { src = X;   dst = base;            }
  else if ((rel -= 1048576) < 262144) { src = Wq;  dst = base + 4194304; }
  else if ((rel -=  262144) < 262144) { src = Wk;  dst = base + 5242880; }
  else if ((rel -=  262144) < 262144) { src = Wv;  dst = base + 6291456; }
  else if ((rel -=  262144) < 262144) { src = Wo;  dst = base + 7340032; }
  else if ((rel -=  262144) <  32768) { src = Wg1; dst = base + 8388608; }
  else if ((rel -=   32768) <  32768) { src = Wg2; dst = base + 8519680; }
  else   { rel -= 32768;                src = gnw; dst = base + 8650752; }
  float4 v = ((const float4*)src)[rel];
  ushort4 o; o.x=f2bu(v.x); o.y=f2bu(v.y); o.z=f2bu(v.z); o.w=f2bu(v.w);
  ((ushort4*)dst)[rel] = o;
}

// ---------------- MFMA GEMM core: C(128x128) = A @ B^T, bf16, fp32 acc ----
__device__ __forceinline__ void gemm_core(
    const unsigned short* __restrict__ A, const unsigned short* __restrict__ B,
    int K, int row0, int col0,
    unsigned short* sA, unsigned short* sB, f32x4 acc[4][4], int tid)
{
  const int lane = tid & 63;
  const int wm = (tid >> 6) & 1, wn = tid >> 7;
  const int wb = tid & 192;                // wave-uniform chunk base
  for (int k0 = 0; k0 < K; k0 += 32){
    __syncthreads();                       // prev iter's LDS reads done
#pragma unroll
    for (int r = 0; r < 2; ++r){
      int idx  = r*256 + tid;              // 512 chunks of 16B per tile
      int mrow = idx >> 2, kc = (idx & 3) * 8;
      async16(A + (size_t)(row0 + mrow)*K + k0 + kc, sA + (size_t)(r*256 + wb)*8);
      async16(B + (size_t)(col0 + mrow)*K + k0 + kc, sB + (size_t)(r*256 + wb)*8);
    }
    __syncthreads();                       // drains vmcnt before barrier
    short8 av[4], bv[4];
#pragma unroll
    for (int i=0;i<4;i++)
      av[i] = *(const short8*)(sA + (size_t)(wm*64 + i*16 + (lane&15))*32 + (lane>>4)*8);
#pragma unroll
    for (int j=0;j<4;j++)
      bv[j] = *(const short8*)(sB + (size_t)(wn*64 + j*16 + (lane&15))*32 + (lane>>4)*8);
#pragma unroll
    for (int i=0;i<4;i++)
#pragma unroll
      for (int j=0;j<4;j++)
        acc[i][j] = __builtin_amdgcn_mfma_f32_16x16x32_bf16(av[i], bv[j], acc[i][j], 0, 0, 0);
  }
}

// bf16 epilogue via LDS: 4 passes of 32 rows; coalesced b128 copy-out.
__device__ __forceinline__ void epilogue_lds(
    f32x4 acc[4][4], int row0, int col0, int tid, int ldc, int act,
    unsigned short* __restrict__ Cb, unsigned short* sC)
{
  const int lane = tid & 63;
  const int wm = (tid >> 6) & 1, wn = tid >> 7;
#pragma unroll
  for (int p=0;p<4;p++){
    __syncthreads();
    if (wm == (p>>1)){
#pragma unroll
      for (int ii=0; ii<2; ii++){
        int i = (p&1)*2 + ii;
        int lr = i*16 + ((lane>>4)<<2) - (p&1)*32;   // local row in [0,32)
#pragma unroll
        for (int j=0;j<4;j++){
          int col = wn*64 + j*16 + (lane&15);
#pragma unroll
          for (int r=0;r<4;r++){
            float v = acc[i][j][r];
            if (act) v = v / (1.f + __expf(-v));
            sC[(lr+r)*128 + col] = f2bu(v);
          }
        }
      }
    }
    __syncthreads();
#pragma unroll
    for (int c = tid; c < 512; c += 256){  // 32 rows x 256B
      int rr = c >> 4, off = (c & 15)*8;
      *(uint4*)&Cb[(size_t)(row0 + p*32 + rr)*ldc + col0 + off] =
          *(const uint4*)&sC[rr*128 + off];
    }
  }
}

// fp32 direct epilogue (64B full-line segments).
__device__ __forceinline__ void epilogue_f32(
    f32x4 acc[4][4], int row0, int col0, int tid, int ldc,
    float* __restrict__ Cf)
{
  const int lane = tid & 63;
  const int wm = (tid >> 6) & 1, wn = tid >> 7;
#pragma unroll
  for (int i=0;i<4;i++){
    int rbase = row0 + wm*64 + i*16 + ((lane>>4)<<2);
#pragma unroll
    for (int j=0;j<4;j++){
      int col = col0 + wn*64 + j*16 + (lane&15);
#pragma unroll
      for (int r=0;r<4;r++)
        Cf[(size_t)(rbase + r)*ldc + col] = acc[i][j][r];
    }
  }
}

// Fused QKV+G1 projection. grid (32, 25).
__global__ __launch_bounds__(256, 2) void proj_kernel(
    const unsigned short* __restrict__ X,
    const unsigned short* __restrict__ Wq, const unsigned short* __restrict__ Wk,
    const unsigned short* __restrict__ Wv, const unsigned short* __restrict__ Wg1,
    unsigned short* __restrict__ Qb, unsigned short* __restrict__ Kb,
    unsigned short* __restrict__ Vb, unsigned short* __restrict__ G1b)
{
  __shared__ unsigned short sA[128*32], sB[128*32];
  int tid = threadIdx.x;
  int which = blockIdx.y >> 3;
  const unsigned short* Bp = (which==0)?Wq:(which==1)?Wk:(which==2)?Wv:Wg1;
  int row0 = blockIdx.x * 128;
  int col0 = (which==3) ? 0 : (blockIdx.y & 7) * 128;
  f32x4 acc[4][4] = {};
  gemm_core(X, Bp, HIDN, row0, col0, sA, sB, acc, tid);
  if      (which==0) epilogue_lds(acc,row0,col0,tid,HIDN,1,Qb, sA);
  else if (which==1) epilogue_lds(acc,row0,col0,tid,HIDN,0,Kb, sA);
  else if (which==2) epilogue_lds(acc,row0,col0,tid,HIDN,0,Vb, sA);
  else               epilogue_lds(acc,row0,col0,tid,128 ,0,G1b,sA);
}

// Generic A@B^T.
__global__ __launch_bounds__(256, 2) void gemm_bt(
    const unsigned short* __restrict__ A, const unsigned short* __restrict__ B,
    int K, int ldc, int act, float* __restrict__ Cf,
    unsigned short* __restrict__ Cb)
{
  __shared__ unsigned short sA[128*32], sB[128*32];
  int tid = threadIdx.x;
  int row0 = blockIdx.x * 128, col0 = blockIdx.y * 128;
  f32x4 acc[4][4] = {};
  gemm_core(A, B, K, row0, col0, sA, sB, acc, tid);
  if (Cb) epilogue_lds(acc, row0, col0, tid, ldc, act, Cb, sA);
  else    epilogue_f32(acc, row0, col0, tid, ldc, Cf);
}

// ---------------- pass 1: per-chunk Esum, Ut = (e^T V)^T  [v][k] ----------
__global__ __launch_bounds__(256) void attn_pass1(
    const unsigned short* __restrict__ Kb, const unsigned short* __restrict__ Vb,
    unsigned short* __restrict__ U, float* __restrict__ Esum)
{
  __shared__ unsigned short se[128*128];  // e (bf16 bits), 32 KB
  __shared__ unsigned short sv[128*128];  // v chunk, 32 KB
  int tid = threadIdx.x;
  int bh = blockIdx.x >> 4, ch = blockIdx.x & 15;
  int b = bh >> 3, h = bh & 7;
  size_t rowbase = (size_t)(b*T_SEQ + ch*128)*HIDN + h*128;

#pragma unroll
  for (int i=0;i<8;i++){                  // K chunk -> e : 2048 uint4
    int u = tid + i*256; int t = u >> 4, kc = (u & 15)*8;
    float kv[8]; up8(&Kb[rowbase + (size_t)t*HIDN + kc], kv);
    ushort4 a, c;
    a.x=f2bu(__expf(kv[0])); a.y=f2bu(__expf(kv[1]));
    a.z=f2bu(__expf(kv[2])); a.w=f2bu(__expf(kv[3]));
    c.x=f2bu(__expf(kv[4])); c.y=f2bu(__expf(kv[5]));
    c.z=f2bu(__expf(kv[6])); c.w=f2bu(__expf(kv[7]));
    *(ushort4*)&se[t*128 + kc    ] = a;
    *(ushort4*)&se[t*128 + kc + 4] = c;
  }
#pragma unroll
  for (int i=0;i<8;i++){                  // V chunk: 2048 uint4
    int u = tid + i*256; int t = u >> 4, kc = (u & 15)*8;
    ((uint4*)sv)[u] = *(const uint4*)&Vb[rowbase + (size_t)t*HIDN + kc];
  }
  __syncthreads();

  if (tid < 128){                         // per-chunk column sums of e
    float s = 0.f;
#pragma unroll 8
    for (int t=0;t<128;t++) s += bu2f(se[t*128 + tid]);
    Esum[(size_t)blockIdx.x*128 + tid] = s;
  }

  int kg = tid >> 4, vg = tid & 15;
  int k0 = kg*8, v0 = vg*8;
  float uacc[8][8] = {};
  for (int s=0;s<128;s++){
    float ev[8], vv[8];
    up8(&se[s*128 + k0], ev);
    up8(&sv[s*128 + v0], vv);
#pragma unroll
    for (int i=0;i<8;i++)
#pragma unroll
      for (int j=0;j<8;j++) uacc[i][j] += ev[i]*vv[j];
  }
  unsigned short* Ub = U + (size_t)blockIdx.x*16384;
#pragma unroll
  for (int j=0;j<8;j++){                  // TRANSPOSED store: Ut[v][k]
    ushort4 w0, w1;
    w0.x=f2bu(uacc[0][j]); w0.y=f2bu(uacc[1][j]); w0.z=f2bu(uacc[2][j]); w0.w=f2bu(uacc[3][j]);
    w1.x=f2bu(uacc[4][j]); w1.y=f2bu(uacc[5][j]); w1.z=f2bu(uacc[6][j]); w1.w=f2bu(uacc[7][j]);
    *(ushort4*)&Ub[(v0+j)*128 + k0    ] = w0;
    *(ushort4*)&Ub[(v0+j)*128 + k0 + 4] = w1;
  }
}

// ---------------- pass 2: exclusive prefix over chunks (in place) ----------
__global__ __launch_bounds__(256) void attn_pass2(
    unsigned short* __restrict__ U, float* __restrict__ Esum)
{
  int bh = blockIdx.x >> 4, sl = blockIdx.x & 15;
  int p = sl*1024 + threadIdx.x*4;
  float r0=0.f, r1=0.f, r2=0.f, r3=0.f;
  for (int c=0;c<16;c++){
    ushort4* ptr = (ushort4*)&U[(size_t)(bh*16 + c)*16384 + p];
    ushort4 t = *ptr;
    ushort4 w;
    w.x=f2bu(r0); w.y=f2bu(r1); w.z=f2bu(r2); w.w=f2bu(r3);
    *ptr = w;
    r0 += bu2f(t.x); r1 += bu2f(t.y); r2 += bu2f(t.z); r3 += bu2f(t.w);
  }
  if (sl == 0 && threadIdx.x < 128){
    float r = 0.f;
    for (int c=0;c<16;c++){
      float* q = &Esum[(size_t)(bh*16 + c)*128 + threadIdx.x];
      float t = *q; *q = r; r += t;
    }
  }
}

// ---------------- pass 3 (MFMA): o = qn@Cprev + causal(qn@e^T)@V ----------
// 512 thr, 8 waves (wm=w&3: 32-row band; wn=w>>2: 64-col band).
// LDS: bufA Q->qn->P ; bufB e->Vt ; bufC Ut->O-staging. 128xLDSP each.
__global__ __launch_bounds__(512, 2) void attn_pass3(
    const unsigned short* __restrict__ Kb, const unsigned short* __restrict__ Qb,
    const unsigned short* __restrict__ Vb, const unsigned short* __restrict__ U,
    const float* __restrict__ Esum, unsigned short* __restrict__ Oatt)
{
  __shared__ unsigned short smem[3*128*LDSP];     // 102 KB
  __shared__ float seg_part[4*128];               // cumsum segment partials
  unsigned short* bufA = smem;
  unsigned short* bufB = smem + 128*LDSP;
  unsigned short* bufC = smem + 2*128*LDSP;

  int tid = threadIdx.x;
  const int lane = tid & 63, quad = lane >> 4;
  const int w = tid >> 6, wm = w & 3, wn = w >> 2;
  const int Rb = wm*32, Cb = wn*64;
  int bh = blockIdx.x >> 4, ch = blockIdx.x & 15;
  int b = bh >> 3, h = bh & 7;
  size_t rowbase = (size_t)(b*T_SEQ + ch*128)*HIDN + h*128;

  // ---- stage Q, e=exp(K), Ut ----
#pragma unroll
  for (int i=0;i<4;i++){
    int u = tid + i*512; int t = u >> 4, kc = (u & 15)*8;
    *(uint4*)&bufA[t*LDSP + kc] = *(const uint4*)&Qb[rowbase + (size_t)t*HIDN + kc];
    float kv[8]; up8(&Kb[rowbase + (size_t)t*HIDN + kc], kv);
    ushort4 a, c;
    a.x=f2bu(__expf(kv[0])); a.y=f2bu(__expf(kv[1]));
    a.z=f2bu(__expf(kv[2])); a.w=f2bu(__expf(kv[3]));
    c.x=f2bu(__expf(kv[4])); c.y=f2bu(__expf(kv[5]));
    c.z=f2bu(__expf(kv[6])); c.w=f2bu(__expf(kv[7]));
    *(ushort4*)&bufB[t*LDSP + kc    ] = a;
    *(ushort4*)&bufB[t*LDSP + kc + 4] = c;
    *(uint4*)&bufC[t*LDSP + kc] =
        *(const uint4*)&U[(size_t)blockIdx.x*16384 + (size_t)t*128 + kc];
  }
  __syncthreads();

  // ---- qn = q*SCALE/E_t ; 4-way segmented inclusive cumsum over t ----
  {
    int col = tid & 127, seg = tid >> 7;           // seg in [0,4)
    float psum = 0.f;
    for (int s = seg*32; s < seg*32+32; ++s) psum += bu2f(bufB[s*LDSP + col]);
    seg_part[seg*128 + col] = psum;
    __syncthreads();
    float run = Esum[(size_t)blockIdx.x*128 + col];
    for (int ss=0; ss<4; ++ss) if (ss < seg) run += seg_part[ss*128 + col];
    for (int s = seg*32; s < seg*32+32; ++s){
      run += bu2f(bufB[s*LDSP + col]);
      float q = bu2f(bufA[s*LDSP + col]);
      bufA[s*LDSP + col] = f2bu(q * SCALE * __builtin_amdgcn_rcpf(run));
    }
  }
  __syncthreads();

  // ---- inter: O = QN @ Ut^T ; scores: P = QN @ E^T ----
  f32x4 accO[2][4] = {}, accP[2][4] = {};
  short8 av[2], bv[4];
#pragma unroll
  for (int k0=0; k0<128; k0+=32){
#pragma unroll
    for (int i=0;i<2;i++)
      av[i] = *(const short8*)(bufA + (Rb + i*16 + (lane&15))*LDSP + k0 + quad*8);
#pragma unroll
    for (int j=0;j<4;j++)
      bv[j] = *(const short8*)(bufC + (Cb + j*16 + (lane&15))*LDSP + k0 + quad*8);
#pragma unroll
    for (int i=0;i<2;i++)
#pragma unroll
      for (int j=0;j<4;j++)
        accO[i][j] = __builtin_amdgcn_mfma_f32_16x16x32_bf16(av[i], bv[j], accO[i][j], 0,0,0);
#pragma unroll
    for (int j=0;j<4;j++)
      bv[j] = *(const short8*)(bufB + (Cb + j*16 + (lane&15))*LDSP + k0 + quad*8);
#pragma unroll
    for (int i=0;i<2;i++)
#pragma unroll
      for (int j=0;j<4;j++)
        accP[i][j] = __builtin_amdgcn_mfma_f32_16x16x32_bf16(av[i], bv[j], accP[i][j], 0,0,0);
  }
  __syncthreads();                // all reads of bufA/bufB done

  // ---- masked P -> bufA [t][s] ; V^T -> bufB [v][s] ----
#pragma unroll
  for (int i=0;i<2;i++){
#pragma unroll
    for (int j=0;j<4;j++){
      int s = Cb + j*16 + (lane&15);
#pragma unroll
      for (int r=0;r<4;r++){
        int t = Rb + i*16 + quad*4 + r;
        bufA[t*LDSP + s] = f2bu(s <= t ? accP[i][j][r] : 0.f);
      }
    }
  }
#pragma unroll
  for (int i=0;i<4;i++){
    int u = tid + i*512; int t = u >> 4, kc = (u & 15)*8;
    unsigned short tmp[8];
    *(uint4*)tmp = *(const uint4*)&Vb[rowbase + (size_t)t*HIDN + kc];
#pragma unroll
    for (int j=0;j<8;j++) bufB[(kc+j)*LDSP + t] = tmp[j];
  }
  __syncthreads();

  // ---- intra: O += P @ Vt^T ----
#pragma unroll
  for (int k0=0; k0<128; k0+=32){
#pragma unroll
    for (int i=0;i<2;i++)
      av[i] = *(const short8*)(bufA + (Rb + i*16 + (lane&15))*LDSP + k0 + quad*8);
#pragma unroll
    for (int j=0;j<4;j++)
      bv[j] = *(const short8*)(bufB + (Cb + j*16 + (lane&15))*LDSP + k0 + quad*8);
#pragma unroll
    for (int i=0;i<2;i++)
#pragma unroll
      for (int j=0;j<4;j++)
        accO[i][j] = __builtin_amdgcn_mfma_f32_16x16x32_bf16(av[i], bv[j], accO[i][j], 0,0,0);
  }
  __syncthreads();                // bufC readers (inter) long done; reuse as staging

  // ---- O -> bufC (bf16) -> coalesced global ----
#pragma unroll
  for (int i=0;i<2;i++){
#pragma unroll
    for (int j=0;j<4;j++){
      int v = Cb + j*16 + (lane&15);
#pragma unroll
      for (int r=0;r<4;r++){
        int t = Rb + i*16 + quad*4 + r;
        bufC[t*LDSP + v] = f2bu(accO[i][j][r]);
      }
    }
  }
  __syncthreads();
#pragma unroll
  for (int i=0;i<4;i++){
    int u = tid + i*512; int t = u >> 4, kc = (u & 15)*8;
    *(uint4*)&Oatt[rowbase + (size_t)t*HIDN + kc] = *(const uint4*)&bufC[t*LDSP + kc];
  }
}

// ---------------- RMSNorm * gnw * swish(gate) -> bf16 ----------------------
__global__ __launch_bounds__(256) void norm_gate(
    const unsigned short* __restrict__ Oatt, const unsigned short* __restrict__ Gt,
    const unsigned short* __restrict__ gnw, unsigned short* __restrict__ Onorm)
{
  int row = blockIdx.x, tid = threadIdx.x;
  ushort4 o4 = *(const ushort4*)&Oatt[(size_t)row*HIDN + tid*4];
  float ox = bu2f(o4.x), oy = bu2f(o4.y), oz = bu2f(o4.z), ow = bu2f(o4.w);
  float ss = ox*ox + oy*oy + oz*oz + ow*ow;
#pragma unroll
  for (int off=32; off>0; off>>=1) ss += __shfl_down(ss, off, 64);
  __shared__ float red[4];
  if ((tid & 63) == 0) red[tid>>6] = ss;
  __syncthreads();
  float rstd = rsqrtf((red[0]+red[1]+red[2]+red[3]) * (1.f/1024.f) + 1e-5f);
  ushort4 g4 = *(const ushort4*)&Gt[(size_t)row*HIDN + tid*4];
  ushort4 w4 = *(const ushort4*)&gnw[tid*4];
  ushort4 r4;
  r4.x = f2bu(ox * rstd * bu2f(w4.x) * bu2f(g4.x));
  r4.y = f2bu(oy * rstd * bu2f(w4.y) * bu2f(g4.y));
  r4.z = f2bu(oz * rstd * bu2f(w4.z) * bu2f(g4.z));
  r4.w = f2bu(ow * rstd * bu2f(w4.w) * bu2f(g4.w));
  *(ushort4*)&Onorm[(size_t)row*HIDN + tid*4] = r4;
}

// ---------------- launch ----------------
extern "C" void kernel_launch(void* const* d_in, const int* in_sizes, int n_in,
                              void* d_out, int out_size, void* d_ws, size_t ws_size,
                              hipStream_t stream) {
  unsigned short* wsS = (unsigned short*)d_ws;     // ~69 MiB used

  unsigned short* Xc   = wsS;              // 4,194,304
  unsigned short* Wqc  = wsS + 4194304;
  unsigned short* Wkc  = wsS + 5242880;
  unsigned short* Wvc  = wsS + 6291456;
  unsigned short* Woc  = wsS + 7340032;
  unsigned short* Wg1c = wsS + 8388608;
  unsigned short* Wg2c = wsS + 8519680;
  unsigned short* gnwc = wsS + 8650752;
  unsigned short* Qb   = wsS + 8651776;
  unsigned short* Kb   = wsS + 12846080;
  unsigned short* Vb   = wsS + 17040384;
  unsigned short* G1b  = wsS + 21234688;
  unsigned short* Gt   = wsS + 21758976;
  unsigned short* Ub   = wsS + 25953280;
  unsigned short* Oattb= wsS + 30147584;
  float*          Esum = (float*)(wsS + 34341888);
  unsigned short* Onorm = Qb;              // Q dead after pass3

  convert_all<<<8449, 256, 0, stream>>>(
      (const float*)d_in[0], (const float*)d_in[1], (const float*)d_in[2],
      (const float*)d_in[3], (const float*)d_in[4], (const float*)d_in[5],
      (const float*)d_in[6], (const float*)d_in[7], wsS);

  proj_kernel<<<dim3(32,25), 256, 0, stream>>>(Xc, Wqc, Wkc, Wvc, Wg1c, Qb, Kb, Vb, G1b);
  gemm_bt   <<<dim3(32,8),  256, 0, stream>>>(G1b, Wg2c, 128, HIDN, 1, nullptr, Gt);
  attn_pass1<<<256, 256, 0, stream>>>(Kb, Vb, Ub, Esum);
  attn_pass2<<<256, 256, 0, stream>>>(Ub, Esum);
  attn_pass3<<<256, 512, 0, stream>>>(Kb, Qb, Vb, Ub, Esum, Oattb);
  norm_gate <<<4096, 256, 0, stream>>>(Oattb, Gt, gnwc, Onorm);
  gemm_bt   <<<dim3(32,8),  256, 0, stream>>>(Onorm, Woc, HIDN, HIDN, 0,
                                              (float*)d_out, nullptr);
}